// Round 2
// baseline (288.411 us; speedup 1.0000x reference)
//
#include <hip/hip_runtime.h>

typedef __attribute__((ext_vector_type(4))) float f32x4;
typedef __attribute__((ext_vector_type(2))) float f32x2;
typedef __attribute__((ext_vector_type(8))) _Float16 f16x8;

#define D 256          // D_in == D_out == 256
#define VBS 128        // ghost batch rows per chunk
#define BN_EPS 1e-5f

// Pack W[k][n] (f32, row-major 256x256) into f16 MFMA B-fragment order:
// wp[((kb*16+ct)*64 + lane)*8 + j] = W[kb*32 + (lane>>4)*8 + j][ct*16 + (lane&15)]
__global__ void pack_w_kernel(const float* __restrict__ W, _Float16* __restrict__ wp) {
    int idx = blockIdx.x * blockDim.x + threadIdx.x;   // [0, 8192)
    int kb  = idx >> 10;          // 8 k-blocks of 32
    int rem = idx & 1023;
    int ct  = rem >> 6;           // 16 col-tiles of 16
    int l   = rem & 63;           // lane
    int col = ct * 16 + (l & 15);
    int k0  = kb * 32 + ((l >> 4) << 3);
    f16x8 v;
#pragma unroll
    for (int j = 0; j < 8; ++j) v[j] = (_Float16)W[(k0 + j) * D + col];
    *reinterpret_cast<f16x8*>(wp + (size_t)idx * 8) = v;
}

// One block per BN chunk of 128 rows. 8 waves; each wave computes 16 rows x 256 cols.
// acc[16] f32x4 = 64 VGPR/thread -> target <=128 total -> 4 waves/SIMD (16/CU).
__global__ __launch_bounds__(512, 4)
void fused_kernel(const float* __restrict__ A, const float* __restrict__ priors,
                  const _Float16* __restrict__ Wp, const float* __restrict__ gamma,
                  const float* __restrict__ beta, float* __restrict__ out) {
    const int chunk = blockIdx.x;
    const int tid   = threadIdx.x;
    const int wid   = tid >> 6;    // 0..7
    const int lane  = tid & 63;
    const int lrow  = lane & 15;   // A-row within 16x16 tile / D-col within tile
    const int lgrp  = lane >> 4;   // k-group in A-frag / row-group in C

    const int row0 = chunk * VBS + wid * 16;

    f32x4 acc[16];
#pragma unroll
    for (int ct = 0; ct < 16; ++ct) {
        f32x4 z = {0.f, 0.f, 0.f, 0.f};
        acc[ct] = z;
    }

    const float* a0 = A + (size_t)(row0 + lrow) * D + lgrp * 8;

    // ---- GEMM: h = a @ W (K = 256 in 8 steps of 32) ----
#pragma unroll
    for (int kb = 0; kb < 8; ++kb) {
        const float* ap = a0 + kb * 32;
        f32x4 lo = *reinterpret_cast<const f32x4*>(ap);
        f32x4 hi = *reinterpret_cast<const f32x4*>(ap + 4);
        f16x8 t;
        t[0] = (_Float16)lo[0]; t[1] = (_Float16)lo[1];
        t[2] = (_Float16)lo[2]; t[3] = (_Float16)lo[3];
        t[4] = (_Float16)hi[0]; t[5] = (_Float16)hi[1];
        t[6] = (_Float16)hi[2]; t[7] = (_Float16)hi[3];
        const f16x8* wpp = reinterpret_cast<const f16x8*>(Wp) + (kb * 16) * 64 + lane;
#pragma unroll
        for (int ct = 0; ct < 16; ++ct) {
            f16x8 bf = wpp[ct * 64];
            acc[ct] = __builtin_amdgcn_mfma_f32_16x16x32_f16(t, bf, acc[ct], 0, 0, 0);
        }
    }

    // ---- Ghost BN stats: per-column sum/sumsq over the block's 128 rows ----
    __shared__ float sSum[8][D];
    __shared__ float sSq[8][D];
#pragma unroll
    for (int ct = 0; ct < 16; ++ct) {
        float s = acc[ct][0] + acc[ct][1] + acc[ct][2] + acc[ct][3];
        float q = acc[ct][0]*acc[ct][0] + acc[ct][1]*acc[ct][1]
                + acc[ct][2]*acc[ct][2] + acc[ct][3]*acc[ct][3];
        s += __shfl_xor(s, 16); q += __shfl_xor(q, 16);
        s += __shfl_xor(s, 32); q += __shfl_xor(q, 32);
        if (lgrp == 0) { sSum[wid][ct * 16 + lrow] = s; sSq[wid][ct * 16 + lrow] = q; }
    }
    __syncthreads();

    __shared__ f32x2 sAB[D];   // {gamma*rstd, beta - mean*gamma*rstd} per column
    if (tid < D) {
        float s = 0.f, q = 0.f;
#pragma unroll
        for (int w = 0; w < 8; ++w) { s += sSum[w][tid]; q += sSq[w][tid]; }
        float mean = s * (1.0f / 128.0f);
        float var  = q * (1.0f / 128.0f) - mean * mean;
        float g    = gamma[tid] * rsqrtf(var + BN_EPS);
        f32x2 ab = {g, beta[tid] - mean * g};
        sAB[tid] = ab;
    }
    __syncthreads();

    // ---- epilogue: BN apply, * priors, batched sparsemax over 4 row-groups ----
    // C layout: col = ct*16 + lrow, row (in-tile) = lgrp*4 + r.
    const float* prb = priors + (size_t)(row0 + lgrp * 4) * D + lrow;

    float m0 = -1e30f, m1 = -1e30f, m2 = -1e30f, m3 = -1e30f;
#pragma unroll
    for (int ct = 0; ct < 16; ++ct) {
        f32x2 ab = sAB[ct * 16 + lrow];
        float x0 = (acc[ct][0] * ab[0] + ab[1]) * prb[0 * D + ct * 16];
        float x1 = (acc[ct][1] * ab[0] + ab[1]) * prb[1 * D + ct * 16];
        float x2 = (acc[ct][2] * ab[0] + ab[1]) * prb[2 * D + ct * 16];
        float x3 = (acc[ct][3] * ab[0] + ab[1]) * prb[3 * D + ct * 16];
        acc[ct][0] = x0; m0 = fmaxf(m0, x0);
        acc[ct][1] = x1; m1 = fmaxf(m1, x1);
        acc[ct][2] = x2; m2 = fmaxf(m2, x2);
        acc[ct][3] = x3; m3 = fmaxf(m3, x3);
    }
#pragma unroll
    for (int o = 8; o >= 1; o >>= 1) {
        m0 = fmaxf(m0, __shfl_xor(m0, o));
        m1 = fmaxf(m1, __shfl_xor(m1, o));
        m2 = fmaxf(m2, __shfl_xor(m2, o));
        m3 = fmaxf(m3, __shfl_xor(m3, o));
    }
#pragma unroll
    for (int ct = 0; ct < 16; ++ct) {
        acc[ct][0] -= m0; acc[ct][1] -= m1; acc[ct][2] -= m2; acc[ct][3] -= m3;
    }

    // Michelot fixed-point for tau, all 4 row-groups in lockstep (4x ILP).
    // tau' = (sum_{z>tau} z - 1)/#{z>tau}; monotone non-decreasing from tau0=-1;
    // converged groups iterate as exact no-ops.
    float t0 = -1.f, t1 = -1.f, t2 = -1.f, t3 = -1.f;
#pragma unroll 1
    for (int it = 0; it < 32; ++it) {
        float s0 = 0.f, c0 = 0.f, s1 = 0.f, c1 = 0.f;
        float s2 = 0.f, c2 = 0.f, s3 = 0.f, c3 = 0.f;
#pragma unroll
        for (int ct = 0; ct < 16; ++ct) {
            float z0 = acc[ct][0], z1 = acc[ct][1], z2 = acc[ct][2], z3 = acc[ct][3];
            if (z0 > t0) { s0 += z0; c0 += 1.f; }
            if (z1 > t1) { s1 += z1; c1 += 1.f; }
            if (z2 > t2) { s2 += z2; c2 += 1.f; }
            if (z3 > t3) { s3 += z3; c3 += 1.f; }
        }
#pragma unroll
        for (int o = 8; o >= 1; o >>= 1) {
            s0 += __shfl_xor(s0, o); c0 += __shfl_xor(c0, o);
            s1 += __shfl_xor(s1, o); c1 += __shfl_xor(c1, o);
            s2 += __shfl_xor(s2, o); c2 += __shfl_xor(c2, o);
            s3 += __shfl_xor(s3, o); c3 += __shfl_xor(c3, o);
        }
        float n0 = (s0 - 1.f) / c0;
        float n1 = (s1 - 1.f) / c1;
        float n2 = (s2 - 1.f) / c2;
        float n3 = (s3 - 1.f) / c3;
        bool done = (n0 <= t0) & (n1 <= t1) & (n2 <= t2) & (n3 <= t3);
        t0 = fmaxf(t0, n0); t1 = fmaxf(t1, n1);
        t2 = fmaxf(t2, n2); t3 = fmaxf(t3, n3);
        if (__all(done)) break;
    }

    float* ob = out + (size_t)(row0 + lgrp * 4) * D + lrow;
#pragma unroll
    for (int ct = 0; ct < 16; ++ct) {
        ob[0 * D + ct * 16] = fmaxf(acc[ct][0] - t0, 0.f);
        ob[1 * D + ct * 16] = fmaxf(acc[ct][1] - t1, 0.f);
        ob[2 * D + ct * 16] = fmaxf(acc[ct][2] - t2, 0.f);
        ob[3 * D + ct * 16] = fmaxf(acc[ct][3] - t3, 0.f);
    }
}

extern "C" void kernel_launch(void* const* d_in, const int* in_sizes, int n_in,
                              void* d_out, int out_size, void* d_ws, size_t ws_size,
                              hipStream_t stream) {
    const float* a      = (const float*)d_in[0];
    const float* priors = (const float*)d_in[1];
    const float* W      = (const float*)d_in[2];
    // d_in[3] = b : unused — ghost-BN mean subtraction cancels any per-column bias.
    const float* gamma  = (const float*)d_in[4];
    const float* beta   = (const float*)d_in[5];
    float* out = (float*)d_out;
    _Float16* wp = (_Float16*)d_ws;   // 256*256 f16 = 128 KB packed W

    const int B = in_sizes[0] / D;        // 262144
    const int nchunks = B / VBS;          // 2048

    hipLaunchKernelGGL(pack_w_kernel, dim3(32), dim3(256), 0, stream, W, wp);
    hipLaunchKernelGGL(fused_kernel, dim3(nchunks), dim3(512), 0, stream,
                       a, priors, wp, gamma, beta, out);
}